// Round 3
// baseline (519.483 us; speedup 1.0000x reference)
//
#include <hip/hip_runtime.h>

#define B_ 16
#define C_ 128
#define N_ 16384
#define TN 32
#define NT 4  // adjacent tiles per block

typedef __attribute__((ext_vector_type(8))) short short8;
typedef __attribute__((ext_vector_type(4))) float f32x4;

__device__ inline unsigned short bf16_rn(float x) {
  unsigned u = __float_as_uint(x);
  unsigned r = u + 0x7FFFu + ((u >> 16) & 1u);
  return (unsigned short)(r >> 16);
}

// Packed f32x2 -> bf16x2 (RNE), 1 VALU inst. No builtin on gfx950 -> inline asm.
__device__ inline unsigned cvt_pk_bf16(float a, float b) {
  unsigned r;
  asm("v_cvt_pk_bf16_f32 %0, %1, %2" : "=v"(r) : "v"(a), "v"(b));
  return r;
}

__device__ inline float u16hi_f(unsigned u) { return __uint_as_float(u & 0xFFFF0000u); }
__device__ inline float u16lo_f(unsigned u) { return __uint_as_float(u << 16); }

// Merged prep: Wk -> bf16 hi/lo split (k-path keeps split precision),
// Wv -> bf16 hi only; block 0 computes wqsum[i] = sum_o Wq[o][i].
__global__ __launch_bounds__(256) void prep_kernel(
    const float* __restrict__ Wq, const float* __restrict__ Wk, const float* __restrict__ Wv,
    float* __restrict__ wqsum,
    unsigned short* __restrict__ WkHi, unsigned short* __restrict__ WkLo,
    unsigned short* __restrict__ WvHi) {
  int idx = blockIdx.x * 256 + threadIdx.x;  // 0..16383
  {
    float x = Wk[idx];
    unsigned short h = bf16_rn(x);
    WkHi[idx] = h;
    WkLo[idx] = bf16_rn(x - __uint_as_float(((unsigned)h) << 16));
  }
  WvHi[idx] = bf16_rn(Wv[idx]);
  if (blockIdx.x == 0 && threadIdx.x < C_) {
    int i = threadIdx.x;
    float s = 0.f;
#pragma unroll 8
    for (int o = 0; o < C_; ++o) s += Wq[o * C_ + i];
    wqsum[i] = s;
  }
}

// Main: one block per (batch, 128-col group) = 4 adjacent 32-col tiles,
// software-pipelined: tile t+1's global loads issue before tile t's GEMMs;
// convert+LDS-write lands after tile t's epilogue (T14 split). 4 waves,
// j-split: wave w owns channels [32w,32w+32) for all 32 cols of a tile.
// k-GEMM split precision (3 mfma), v-GEMM bf16. Epilogue feature from LDS
// hi+lo reconstruct (err ~2^-17), read into regs BEFORE barrier 1 so the
// next tile's staging (after barrier 2) can't race it. Softmax exp2-domain,
// cross-wave via red[0..3] rounds. LDS 34.5 KB -> 4 blocks/CU.
// LDS X layout: [n][i] bf16 rows of 128, 8-chunks XOR-swizzled f(n)=(n&15)^((n>>2)&7).
__global__ __launch_bounds__(256, 4) void csa_mfma_kernel(
    const float* __restrict__ feature, const float* __restrict__ position,
    const float* __restrict__ wqsum,
    const unsigned short* __restrict__ WkHi, const unsigned short* __restrict__ WkLo,
    const unsigned short* __restrict__ WvHi,
    float* __restrict__ out) {
  __shared__ unsigned short posHi[TN * 128];
  __shared__ unsigned short posLo[TN * 128];
  __shared__ unsigned short featHi[TN * 128];
  __shared__ unsigned short featLo[TN * 128];
  __shared__ float red0[4][TN];  // sq wave-partials (written during staging)
  __shared__ float red1[4][TN];  // ksum wave-partials
  __shared__ float red2[4][TN];  // per-wave local max (log2 domain)
  __shared__ float red3[4][TN];  // per-wave exp2-sum

  const int tid = threadIdx.x;
  const int lane = tid & 63;
  const int w = tid >> 6;   // wave: owns j in [32w, 32w+32)
  const int m = lane & 15;  // column-within-16 / A-row
  const int q = lane >> 4;  // quad
  const int b = blockIdx.x >> 7;
  const int ncol0 = (blockIdx.x & 127) * (TN * NT);

  const float* pos_g = position + (size_t)b * C_ * N_ + ncol0;
  const float* feat_g = feature + (size_t)b * C_ * N_ + ncol0;

  // staging thread mapping (same for every tile)
  const int g = tid >> 3;        // 0..31 (wave w covers g in [8w,8w+8))
  const int n4 = (tid & 7) * 4;  // col group
  const float2 wq0 = *(const float2*)(wqsum + 2 * g);
  const float2 wq1 = *(const float2*)(wqsum + 64 + 2 * g);

  // per-column-tile LDS row bases for this lane (col n = nt*16 + m)
  int rb[2], f8[2];
#pragma unroll
  for (int nt = 0; nt < 2; ++nt) {
    int n = nt * 16 + m;
    rb[nt] = n * 128;
    f8[nt] = ((n & 15) ^ ((n >> 2) & 7)) * 8;
  }

  // prefetch registers (reused across tiles; dead after stage_convert)
  float4 P0[2], P1[2], F0[2], F1[2];

  auto issue_loads = [&](int t) {
    const float* pg = pos_g + t * TN;
    const float* fg = feat_g + t * TN;
#pragma unroll
    for (int it = 0; it < 2; ++it) {
      int i = 64 * it + 2 * g;
      P0[it] = *(const float4*)(pg + (size_t)i * N_ + n4);
      P1[it] = *(const float4*)(pg + (size_t)(i + 1) * N_ + n4);
      F0[it] = *(const float4*)(fg + (size_t)i * N_ + n4);
      F1[it] = *(const float4*)(fg + (size_t)(i + 1) * N_ + n4);
    }
  };

  auto stage_convert = [&]() {
    f32x4 sqa = (f32x4){0.f, 0.f, 0.f, 0.f};
#pragma unroll
    for (int it = 0; it < 2; ++it) {
      int i = 64 * it + 2 * g;
      float2 wq2 = it ? wq1 : wq0;
      const float* P0p = (const float*)&P0[it];
      const float* P1p = (const float*)&P1[it];
      const float* F0p = (const float*)&F0[it];
      const float* F1p = (const float*)&F1[it];
      int c8 = (i >> 3) * 8;
      int ioff = i & 7;  // even
#pragma unroll
      for (int d = 0; d < 4; ++d) {
        int n = n4 + d;
        int fn8 = ((n & 15) ^ ((n >> 2) & 7)) * 8;
        int hw = n * 128 + (c8 ^ fn8) + ioff;
        float x0 = P0p[d], x1 = P1p[d];
        unsigned hu = cvt_pk_bf16(x0, x1);
        *(unsigned*)(posHi + hw) = hu;
        float l0 = x0 - u16lo_f(hu);
        float l1 = x1 - u16hi_f(hu);
        *(unsigned*)(posLo + hw) = cvt_pk_bf16(l0, l1);
        float y0 = F0p[d], y1 = F1p[d];
        unsigned fu = cvt_pk_bf16(y0, y1);
        *(unsigned*)(featHi + hw) = fu;
        float e0 = y0 - u16lo_f(fu);
        float e1 = y1 - u16hi_f(fu);
        *(unsigned*)(featLo + hw) = cvt_pk_bf16(e0, e1);
        sqa[d] = fmaf(wq2.x, x0, fmaf(wq2.y, x1, sqa[d]));
      }
    }
#pragma unroll
    for (int d = 0; d < 4; ++d) {
      float s = sqa[d];
      s += __shfl_xor(s, 8, 64);
      s += __shfl_xor(s, 16, 64);
      s += __shfl_xor(s, 32, 64);
      sqa[d] = s;
    }
    if (lane < 8) {
      *(float4*)&red0[w][lane * 4] = make_float4(sqa[0], sqa[1], sqa[2], sqa[3]);
    }
  };

  // ---- prologue: stage tile 0 ----
  issue_loads(0);
  stage_convert();
  __syncthreads();

#pragma unroll
  for (int t = 0; t < NT; ++t) {
    // issue next tile's global loads; latency hides under GEMM+softmax of tile t
    if (t + 1 < NT) issue_loads(t + 1);

    // ---- k-GEMM (split precision): k[j][n], j = 32w + 16jt + 4q + r ----
    f32x4 acck[2][2];
#pragma unroll
    for (int jt = 0; jt < 2; ++jt)
#pragma unroll
      for (int nt = 0; nt < 2; ++nt) acck[jt][nt] = (f32x4){0.f, 0.f, 0.f, 0.f};

#pragma unroll
    for (int jt = 0; jt < 2; ++jt) {
      const int arow = (32 * w + 16 * jt + m) * 128 + q * 8;
      short8 ah[4], al[4];  // weight frags (L2-hot), reused over nt
#pragma unroll
      for (int kk = 0; kk < 4; ++kk) {
        ah[kk] = *(const short8*)(WkHi + arow + kk * 32);
        al[kk] = *(const short8*)(WkLo + arow + kk * 32);
      }
#pragma unroll
      for (int kk = 0; kk < 4; ++kk) {
        int co = (kk * 4 + q) * 8;
        short8 bh0 = *(const short8*)(posHi + rb[0] + (co ^ f8[0]));
        short8 bl0 = *(const short8*)(posLo + rb[0] + (co ^ f8[0]));
        short8 bh1 = *(const short8*)(posHi + rb[1] + (co ^ f8[1]));
        short8 bl1 = *(const short8*)(posLo + rb[1] + (co ^ f8[1]));
        acck[jt][0] = __builtin_amdgcn_mfma_f32_16x16x32_bf16(ah[kk], bh0, acck[jt][0], 0, 0, 0);
        acck[jt][1] = __builtin_amdgcn_mfma_f32_16x16x32_bf16(ah[kk], bh1, acck[jt][1], 0, 0, 0);
        acck[jt][0] = __builtin_amdgcn_mfma_f32_16x16x32_bf16(ah[kk], bl0, acck[jt][0], 0, 0, 0);
        acck[jt][1] = __builtin_amdgcn_mfma_f32_16x16x32_bf16(ah[kk], bl1, acck[jt][1], 0, 0, 0);
        acck[jt][0] = __builtin_amdgcn_mfma_f32_16x16x32_bf16(al[kk], bh0, acck[jt][0], 0, 0, 0);
        acck[jt][1] = __builtin_amdgcn_mfma_f32_16x16x32_bf16(al[kk], bh1, acck[jt][1], 0, 0, 0);
      }
    }

    // ---- ksum partial over this wave's 32 j ----
#pragma unroll
    for (int nt = 0; nt < 2; ++nt) {
      float s = 0.f;
#pragma unroll
      for (int jt = 0; jt < 2; ++jt)
        s += acck[jt][nt][0] + acck[jt][nt][1] + acck[jt][nt][2] + acck[jt][nt][3];
      s += __shfl_xor(s, 16, 64);
      s += __shfl_xor(s, 32, 64);
      if (q == 0) red1[w][nt * 16 + m] = s;
    }

    // ---- v-GEMM (bf16 only) ----
    f32x4 accv[2][2];
#pragma unroll
    for (int jt = 0; jt < 2; ++jt)
#pragma unroll
      for (int nt = 0; nt < 2; ++nt) accv[jt][nt] = (f32x4){0.f, 0.f, 0.f, 0.f};

#pragma unroll
    for (int jt = 0; jt < 2; ++jt) {
      const int arow = (32 * w + 16 * jt + m) * 128 + q * 8;
      short8 ah[4];
#pragma unroll
      for (int kk = 0; kk < 4; ++kk) ah[kk] = *(const short8*)(WvHi + arow + kk * 32);
#pragma unroll
      for (int kk = 0; kk < 4; ++kk) {
        int co = (kk * 4 + q) * 8;
        short8 bh0 = *(const short8*)(featHi + rb[0] + (co ^ f8[0]));
        short8 bh1 = *(const short8*)(featHi + rb[1] + (co ^ f8[1]));
        accv[jt][0] = __builtin_amdgcn_mfma_f32_16x16x32_bf16(ah[kk], bh0, accv[jt][0], 0, 0, 0);
        accv[jt][1] = __builtin_amdgcn_mfma_f32_16x16x32_bf16(ah[kk], bh1, accv[jt][1], 0, 0, 0);
      }
    }

    // ---- epilogue feature reconstruct into regs (LDS reads BEFORE barrier 1,
    //      so next tile's staging writes after barrier 2 can't race them) ----
    float fv[2][2][4];
#pragma unroll
    for (int jt = 0; jt < 2; ++jt) {
      const int jb = 32 * w + 16 * jt + 4 * q;
      const int cj = (jb >> 3) * 8;
      const int joff = jb & 7;
#pragma unroll
      for (int nt = 0; nt < 2; ++nt) {
        int hw = rb[nt] + (cj ^ f8[nt]) + joff;
        unsigned fh01 = *(const unsigned*)(featHi + hw);
        unsigned fl01 = *(const unsigned*)(featLo + hw);
        unsigned fh23 = *(const unsigned*)(featHi + hw + 2);
        unsigned fl23 = *(const unsigned*)(featLo + hw + 2);
        fv[jt][nt][0] = u16lo_f(fh01) + u16lo_f(fl01);
        fv[jt][nt][1] = u16hi_f(fh01) + u16hi_f(fl01);
        fv[jt][nt][2] = u16lo_f(fh23) + u16lo_f(fl23);
        fv[jt][nt][3] = u16hi_f(fh23) + u16hi_f(fl23);
      }
    }

    __syncthreads();  // barrier 1: red0/red1 ready; all tile-LDS reads complete

    // ---- cross-wave: g, then wave-local softmax stats (exp2 domain) ----
    float mw[2], sw[2], attscale[2];
#pragma unroll
    for (int nt = 0; nt < 2; ++nt) {
      int c = nt * 16 + m;
      float ss = red0[0][c] + red0[1][c] + red0[2][c] + red0[3][c];
      float ks = red1[0][c] + red1[1][c] + red1[2][c] + red1[3][c];
      float gl = (ss / (1e-9f + ss * ks)) * 1.44269504f;  // fold log2(e)
      float mx = gl * acck[0][nt][0];
#pragma unroll
      for (int jt = 0; jt < 2; ++jt)
#pragma unroll
        for (int r = 0; r < 4; ++r) {
          float e = gl * acck[jt][nt][r];
          acck[jt][nt][r] = e;  // log2-domain energy
          mx = fmaxf(mx, e);
        }
      mx = fmaxf(mx, __shfl_xor(mx, 16, 64));
      mx = fmaxf(mx, __shfl_xor(mx, 32, 64));
      float s = 0.f;
#pragma unroll
      for (int jt = 0; jt < 2; ++jt)
#pragma unroll
        for (int r = 0; r < 4; ++r) {
          float p = exp2f(acck[jt][nt][r] - mx);
          acck[jt][nt][r] = p;  // unnormalized attention
          s += p;
        }
      s += __shfl_xor(s, 16, 64);
      s += __shfl_xor(s, 32, 64);
      mw[nt] = mx;
      sw[nt] = s;
    }
    if (q == 0) {
#pragma unroll
      for (int nt = 0; nt < 2; ++nt) {
        red2[w][nt * 16 + m] = mw[nt];
        red3[w][nt * 16 + m] = sw[nt];
      }
    }
    __syncthreads();  // barrier 2: red2/red3 ready
#pragma unroll
    for (int nt = 0; nt < 2; ++nt) {
      int c = nt * 16 + m;
      float M = red2[0][c];
      M = fmaxf(M, red2[1][c]);
      M = fmaxf(M, red2[2][c]);
      M = fmaxf(M, red2[3][c]);
      float es = red3[0][c] * exp2f(red2[0][c] - M);
      es += red3[1][c] * exp2f(red2[1][c] - M);
      es += red3[2][c] * exp2f(red2[2][c] - M);
      es += red3[3][c] * exp2f(red2[3][c] - M);
      attscale[nt] = exp2f(mw[nt] - M) / es;  // es >= 1 (max-owning wave)
    }

    // ---- epilogue: out = att*v + feature (fv from regs) ----
    float* outp = out + (size_t)b * C_ * N_ + ncol0 + t * TN + m;
#pragma unroll
    for (int jt = 0; jt < 2; ++jt) {
      const int jb = 32 * w + 16 * jt + 4 * q;
#pragma unroll
      for (int nt = 0; nt < 2; ++nt) {
        float as = attscale[nt];
        size_t base = (size_t)jb * N_ + nt * 16;
        outp[base] = fmaf(acck[jt][nt][0] * as, accv[jt][nt][0], fv[jt][nt][0]);
        outp[base + N_] = fmaf(acck[jt][nt][1] * as, accv[jt][nt][1], fv[jt][nt][1]);
        outp[base + (size_t)2 * N_] = fmaf(acck[jt][nt][2] * as, accv[jt][nt][2], fv[jt][nt][2]);
        outp[base + (size_t)3 * N_] = fmaf(acck[jt][nt][3] * as, accv[jt][nt][3], fv[jt][nt][3]);
      }
    }

    // ---- stage next tile (loads already in flight since loop top) ----
    if (t + 1 < NT) {
      stage_convert();
      __syncthreads();  // barrier 3: next tile's LDS + red0 ready
    }
  }
}

extern "C" void kernel_launch(void* const* d_in, const int* in_sizes, int n_in,
                              void* d_out, int out_size, void* d_ws, size_t ws_size,
                              hipStream_t stream) {
  const float* feature = (const float*)d_in[0];
  const float* position = (const float*)d_in[1];
  const float* Wq = (const float*)d_in[2];
  const float* Wk = (const float*)d_in[3];
  const float* Wv = (const float*)d_in[4];
  float* out = (float*)d_out;

  char* ws = (char*)d_ws;
  float* wqsum = (float*)ws;                           // 512 B
  unsigned short* WkHi = (unsigned short*)(ws + 512);  // 32 KB each
  unsigned short* WkLo = (unsigned short*)(ws + 512 + 32768);
  unsigned short* WvHi = (unsigned short*)(ws + 512 + 65536);

  prep_kernel<<<64, 256, 0, stream>>>(Wq, Wk, Wv, wqsum, WkHi, WkLo, WvHi);
  csa_mfma_kernel<<<B_ * (N_ / (TN * NT)), 256, 0, stream>>>(feature, position, wqsum,
                                                             WkHi, WkLo, WvHi, out);
}

// Round 4
// 481.376 us; speedup vs baseline: 1.0792x; 1.0792x over previous
//
#include <hip/hip_runtime.h>

#define B_ 16
#define C_ 128
#define N_ 16384

typedef __attribute__((ext_vector_type(8))) short short8;
typedef __attribute__((ext_vector_type(4))) float f32x4;
typedef __attribute__((ext_vector_type(4))) unsigned u32x4;

__device__ inline unsigned short bf16_rn(float x) {
  unsigned u = __float_as_uint(x);
  unsigned r = u + 0x7FFFu + ((u >> 16) & 1u);
  return (unsigned short)(r >> 16);
}

// Packed f32x2 -> bf16x2 (RNE), 1 VALU inst. No builtin on gfx950 -> inline asm.
__device__ inline unsigned cvt_pk_bf16(float a, float b) {
  unsigned r;
  asm("v_cvt_pk_bf16_f32 %0, %1, %2" : "=v"(r) : "v"(a), "v"(b));
  return r;
}

__device__ inline float u16hi_f(unsigned u) { return __uint_as_float(u & 0xFFFF0000u); }
__device__ inline float u16lo_f(unsigned u) { return __uint_as_float(u << 16); }

// Merged prep: Wk -> bf16 hi/lo split (k-path keeps split precision),
// Wv -> bf16 hi only; block 0 computes wqsum[i] = sum_o Wq[o][i].
__global__ __launch_bounds__(256) void prep_kernel(
    const float* __restrict__ Wq, const float* __restrict__ Wk, const float* __restrict__ Wv,
    float* __restrict__ wqsum,
    unsigned short* __restrict__ WkHi, unsigned short* __restrict__ WkLo,
    unsigned short* __restrict__ WvHi) {
  int idx = blockIdx.x * 256 + threadIdx.x;  // 0..16383
  {
    float x = Wk[idx];
    unsigned short h = bf16_rn(x);
    WkHi[idx] = h;
    WkLo[idx] = bf16_rn(x - __uint_as_float(((unsigned)h) << 16));
  }
  WvHi[idx] = bf16_rn(Wv[idx]);
  if (blockIdx.x == 0 && threadIdx.x < C_) {
    int i = threadIdx.x;
    float s = 0.f;
#pragma unroll 8
    for (int o = 0; o < C_; ++o) s += Wq[o * C_ + i];
    wqsum[i] = s;
  }
}

// Main: barrier-free, LDS-free. One block = 4 waves; wave w owns 16 columns
// (col = blk*64 + w*16 + m) and ALL 128 output channels j. Everything is
// wave-local: sq/ksum/softmax reduce over the quad axis (shfl_xor 16,32).
// B-frags load directly from global (row-strided dwords, coalesced over m;
// block's 64 cols = aligned 256B lines). Weight A-frags: same addresses in
// all 4 waves, one kk-slice = 24 KB -> L1-resident. k-GEMM split precision
// (3 mfma), v-GEMM bf16. Epilogue feature read exact f32 from global (L1/L2
// hot from the v-path reads). ~160 independent VMEM/wave-tile, no barriers.
__global__ __launch_bounds__(256, 4) void csa_mfma_kernel(
    const float* __restrict__ feature, const float* __restrict__ position,
    const float* __restrict__ wqsum,
    const unsigned short* __restrict__ WkHi, const unsigned short* __restrict__ WkLo,
    const unsigned short* __restrict__ WvHi,
    float* __restrict__ out) {
  const int tid = threadIdx.x;
  const int lane = tid & 63;
  const int w = tid >> 6;   // wave -> 16-col group
  const int m = lane & 15;  // col within group / A row
  const int q = lane >> 4;  // quad
  const int b = blockIdx.x >> 8;  // 256 col-blocks of 64 cols per batch
  const int col = (blockIdx.x & 255) * 64 + w * 16 + m;

  const float* pos_g = position + (size_t)b * C_ * N_ + col;
  const float* feat_g = feature + (size_t)b * C_ * N_ + col;

  f32x4 acck[8], accv[8];
#pragma unroll
  for (int jt = 0; jt < 8; ++jt) {
    acck[jt] = (f32x4){0.f, 0.f, 0.f, 0.f};
    accv[jt] = (f32x4){0.f, 0.f, 0.f, 0.f};
  }

  float sq = 0.f;

#pragma unroll
  for (int kk = 0; kk < 4; ++kk) {
    const int i0 = kk * 32 + q * 8;  // this lane's 8 k-rows for this slice
    // 16 independent row-strided loads (coalesced 64B segments over m-lanes)
    float ps[8], fs[8];
#pragma unroll
    for (int s = 0; s < 8; ++s) {
      ps[s] = pos_g[(size_t)(i0 + s) * N_];
      fs[s] = feat_g[(size_t)(i0 + s) * N_];
    }
    // sq partial on exact f32 data
    float4 wqa = *(const float4*)(wqsum + i0);
    float4 wqb = *(const float4*)(wqsum + i0 + 4);
    sq = fmaf(wqa.x, ps[0], sq);
    sq = fmaf(wqa.y, ps[1], sq);
    sq = fmaf(wqa.z, ps[2], sq);
    sq = fmaf(wqa.w, ps[3], sq);
    sq = fmaf(wqb.x, ps[4], sq);
    sq = fmaf(wqb.y, ps[5], sq);
    sq = fmaf(wqb.z, ps[6], sq);
    sq = fmaf(wqb.w, ps[7], sq);
    // build B-frags: pos hi/lo split, feat hi only
    u32x4 bh4, bl4, fh4;
#pragma unroll
    for (int d = 0; d < 4; ++d) {
      unsigned h = cvt_pk_bf16(ps[2 * d], ps[2 * d + 1]);
      bh4[d] = h;
      float l0 = ps[2 * d] - u16lo_f(h);
      float l1 = ps[2 * d + 1] - u16hi_f(h);
      bl4[d] = cvt_pk_bf16(l0, l1);
      fh4[d] = cvt_pk_bf16(fs[2 * d], fs[2 * d + 1]);
    }
    short8 bh = __builtin_bit_cast(short8, bh4);
    short8 bl = __builtin_bit_cast(short8, bl4);
    short8 fh = __builtin_bit_cast(short8, fh4);
    // 8 j-tiles; weight frags transient (L1-hot, same addrs in all waves)
#pragma unroll
    for (int jt = 0; jt < 8; ++jt) {
      const int arow = (16 * jt + m) * 128 + kk * 32 + q * 8;
      short8 ah = *(const short8*)(WkHi + arow);
      short8 al = *(const short8*)(WkLo + arow);
      short8 vh = *(const short8*)(WvHi + arow);
      acck[jt] = __builtin_amdgcn_mfma_f32_16x16x32_bf16(ah, bh, acck[jt], 0, 0, 0);
      acck[jt] = __builtin_amdgcn_mfma_f32_16x16x32_bf16(ah, bl, acck[jt], 0, 0, 0);
      acck[jt] = __builtin_amdgcn_mfma_f32_16x16x32_bf16(al, bh, acck[jt], 0, 0, 0);
      accv[jt] = __builtin_amdgcn_mfma_f32_16x16x32_bf16(vh, fh, accv[jt], 0, 0, 0);
    }
  }

  // ---- wave-local reductions over the quad axis ----
  sq += __shfl_xor(sq, 16, 64);
  sq += __shfl_xor(sq, 32, 64);

  float ksum = 0.f;
#pragma unroll
  for (int jt = 0; jt < 8; ++jt)
    ksum += acck[jt][0] + acck[jt][1] + acck[jt][2] + acck[jt][3];
  ksum += __shfl_xor(ksum, 16, 64);
  ksum += __shfl_xor(ksum, 32, 64);

  float gl = (sq / (1e-9f + sq * ksum)) * 1.44269504f;  // fold log2(e)

  float mx = gl * acck[0][0];
#pragma unroll
  for (int jt = 0; jt < 8; ++jt)
#pragma unroll
    for (int r = 0; r < 4; ++r) {
      float e = gl * acck[jt][r];
      acck[jt][r] = e;  // log2-domain energy
      mx = fmaxf(mx, e);
    }
  mx = fmaxf(mx, __shfl_xor(mx, 16, 64));
  mx = fmaxf(mx, __shfl_xor(mx, 32, 64));

  float esum = 0.f;
#pragma unroll
  for (int jt = 0; jt < 8; ++jt)
#pragma unroll
    for (int r = 0; r < 4; ++r) {
      float p = exp2f(acck[jt][r] - mx);
      acck[jt][r] = p;  // unnormalized attention
      esum += p;
    }
  esum += __shfl_xor(esum, 16, 64);
  esum += __shfl_xor(esum, 32, 64);
  float inv = 1.0f / esum;

  // ---- epilogue: out = att*v + feature (exact f32 residual, hot lines) ----
  float* outp = out + (size_t)b * C_ * N_ + col;
#pragma unroll
  for (int jt = 0; jt < 8; ++jt) {
    const size_t rowb = (size_t)(16 * jt + 4 * q) * N_;
    float f0 = feat_g[rowb];
    float f1 = feat_g[rowb + N_];
    float f2 = feat_g[rowb + (size_t)2 * N_];
    float f3 = feat_g[rowb + (size_t)3 * N_];
    outp[rowb] = fmaf(acck[jt][0] * inv, accv[jt][0], f0);
    outp[rowb + N_] = fmaf(acck[jt][1] * inv, accv[jt][1], f1);
    outp[rowb + (size_t)2 * N_] = fmaf(acck[jt][2] * inv, accv[jt][2], f2);
    outp[rowb + (size_t)3 * N_] = fmaf(acck[jt][3] * inv, accv[jt][3], f3);
  }
}

extern "C" void kernel_launch(void* const* d_in, const int* in_sizes, int n_in,
                              void* d_out, int out_size, void* d_ws, size_t ws_size,
                              hipStream_t stream) {
  const float* feature = (const float*)d_in[0];
  const float* position = (const float*)d_in[1];
  const float* Wq = (const float*)d_in[2];
  const float* Wk = (const float*)d_in[3];
  const float* Wv = (const float*)d_in[4];
  float* out = (float*)d_out;

  char* ws = (char*)d_ws;
  float* wqsum = (float*)ws;                           // 512 B
  unsigned short* WkHi = (unsigned short*)(ws + 512);  // 32 KB each
  unsigned short* WkLo = (unsigned short*)(ws + 512 + 32768);
  unsigned short* WvHi = (unsigned short*)(ws + 512 + 65536);

  prep_kernel<<<64, 256, 0, stream>>>(Wq, Wk, Wv, wqsum, WkHi, WkLo, WvHi);
  csa_mfma_kernel<<<B_ * 256, 256, 0, stream>>>(feature, position, wqsum,
                                                WkHi, WkLo, WvHi, out);
}

// Round 5
// 436.124 us; speedup vs baseline: 1.1911x; 1.1038x over previous
//
#include <hip/hip_runtime.h>

#define B_ 16
#define C_ 128
#define N_ 16384
#define TN 32

typedef __attribute__((ext_vector_type(8))) short short8;
typedef __attribute__((ext_vector_type(4))) float f32x4;

__device__ inline unsigned short bf16_rn(float x) {
  unsigned u = __float_as_uint(x);
  unsigned r = u + 0x7FFFu + ((u >> 16) & 1u);
  return (unsigned short)(r >> 16);
}

// Packed f32x2 -> bf16x2 (RNE), 1 VALU inst. No builtin on gfx950 -> inline asm.
__device__ inline unsigned cvt_pk_bf16(float a, float b) {
  unsigned r;
  asm("v_cvt_pk_bf16_f32 %0, %1, %2" : "=v"(r) : "v"(a), "v"(b));
  return r;
}

__device__ inline float u16hi_f(unsigned u) { return __uint_as_float(u & 0xFFFF0000u); }
__device__ inline float u16lo_f(unsigned u) { return __uint_as_float(u << 16); }

// Merged prep: Wk -> bf16 hi/lo split (k-path keeps split precision),
// Wv -> bf16 hi only; block 0 computes wqsum[i] = sum_o Wq[o][i].
__global__ __launch_bounds__(256) void prep_kernel(
    const float* __restrict__ Wq, const float* __restrict__ Wk, const float* __restrict__ Wv,
    float* __restrict__ wqsum,
    unsigned short* __restrict__ WkHi, unsigned short* __restrict__ WkLo,
    unsigned short* __restrict__ WvHi) {
  int idx = blockIdx.x * 256 + threadIdx.x;  // 0..16383
  {
    float x = Wk[idx];
    unsigned short h = bf16_rn(x);
    WkHi[idx] = h;
    WkLo[idx] = bf16_rn(x - __uint_as_float(((unsigned)h) << 16));
  }
  WvHi[idx] = bf16_rn(Wv[idx]);
  if (blockIdx.x == 0 && threadIdx.x < C_) {
    int i = threadIdx.x;
    float s = 0.f;
#pragma unroll 8
    for (int o = 0; o < C_; ++o) s += Wq[o * C_ + i];
    wqsum[i] = s;
  }
}

// Main: one block per (batch, 32-col tile). 4 waves, j-split: wave w owns output
// channels [32w,32w+32) for all 32 cols. LDS time-multiplexed: xHi/xLo hold the
// POS tile (hi/lo) for the k-GEMM, then are overwritten with the FEAT tile
// (hi/lo) for the v-GEMM + residual reconstruct. 18.4 KB LDS -> 8 blocks/CU
// (32 waves/CU, 100% nominal); __launch_bounds__(256,8) caps VGPR at 64.
// Phases: stage pos (+sq->red0) | B0 | k-GEMM (split, 48 mfma) | ksum->red1 |
// B1 | softmax-local (energies, mx, esum -> red2/3) + re-stage feat | B2 |
// attscale combine + v-GEMM (bf16, 16 mfma) + epilogue (fv = hi+lo from LDS).
// Same 3 barriers as R2. LDS X layout: [n][i] bf16 rows of 128, 8-chunks
// XOR-swizzled f(n)=(n&15)^((n>>2)&7).
__global__ __launch_bounds__(256, 8) void csa_mfma_kernel(
    const float* __restrict__ feature, const float* __restrict__ position,
    const float* __restrict__ wqsum,
    const unsigned short* __restrict__ WkHi, const unsigned short* __restrict__ WkLo,
    const unsigned short* __restrict__ WvHi,
    float* __restrict__ out) {
  __shared__ unsigned short xHi[TN * 128];
  __shared__ unsigned short xLo[TN * 128];
  __shared__ float red0[4][TN];  // sq wave-partials (written during pos staging)
  __shared__ float red1[4][TN];  // ksum wave-partials
  __shared__ float red2[4][TN];  // per-wave local max (log2 domain)
  __shared__ float red3[4][TN];  // per-wave exp2-sum

  const int tid = threadIdx.x;
  const int lane = tid & 63;
  const int w = tid >> 6;   // wave: owns j in [32w, 32w+32)
  const int m = lane & 15;  // column-within-16 / A-row
  const int q = lane >> 4;  // quad
  const int b = blockIdx.x >> 9;
  const int n0 = (blockIdx.x & 511) * TN;

  const float* pos_g = position + (size_t)b * C_ * N_ + n0;
  const float* feat_g = feature + (size_t)b * C_ * N_ + n0;

  // staging thread mapping
  const int g = tid >> 3;        // 0..31 (wave w covers g in [8w,8w+8))
  const int n4 = (tid & 7) * 4;  // col group

  // per-column-tile LDS row bases for this lane (col n = nt*16 + m)
  int rb[2], f8[2];
#pragma unroll
  for (int nt = 0; nt < 2; ++nt) {
    int n = nt * 16 + m;
    rb[nt] = n * 128;
    f8[nt] = ((n & 15) ^ ((n >> 2) & 7)) * 8;
  }

  // ---- phase 1: stage POS tile (hi/lo) + sq partials on exact f32 ----
  {
    f32x4 sqa = (f32x4){0.f, 0.f, 0.f, 0.f};
#pragma unroll
    for (int it = 0; it < 2; ++it) {
      int i = 64 * it + 2 * g;  // even row; rows i, i+1
      float4 p0 = *(const float4*)(pos_g + (size_t)i * N_ + n4);
      float4 p1 = *(const float4*)(pos_g + (size_t)(i + 1) * N_ + n4);
      float2 wq2 = *(const float2*)(wqsum + i);
      const float* P0 = (const float*)&p0;
      const float* P1 = (const float*)&p1;
      int c8 = (i >> 3) * 8;
      int ioff = i & 7;  // even
#pragma unroll
      for (int d = 0; d < 4; ++d) {
        int n = n4 + d;
        int fn8 = ((n & 15) ^ ((n >> 2) & 7)) * 8;
        int hw = n * 128 + (c8 ^ fn8) + ioff;
        float x0 = P0[d], x1 = P1[d];
        unsigned hu = cvt_pk_bf16(x0, x1);
        *(unsigned*)(xHi + hw) = hu;
        float l0 = x0 - u16lo_f(hu);
        float l1 = x1 - u16hi_f(hu);
        *(unsigned*)(xLo + hw) = cvt_pk_bf16(l0, l1);
        sqa[d] = fmaf(wq2.x, x0, fmaf(wq2.y, x1, sqa[d]));
      }
    }
#pragma unroll
    for (int d = 0; d < 4; ++d) {
      float s = sqa[d];
      s += __shfl_xor(s, 8, 64);
      s += __shfl_xor(s, 16, 64);
      s += __shfl_xor(s, 32, 64);
      sqa[d] = s;
    }
    if (lane < 8) {
      *(float4*)&red0[w][lane * 4] = make_float4(sqa[0], sqa[1], sqa[2], sqa[3]);
    }
  }
  __syncthreads();  // B0: pos LDS + red0 ready

  // ---- phase 2: k-GEMM (split precision): k[j][n], j = 32w + 16jt + 4q + r ----
  f32x4 acck[2][2];
#pragma unroll
  for (int jt = 0; jt < 2; ++jt)
#pragma unroll
    for (int nt = 0; nt < 2; ++nt) acck[jt][nt] = (f32x4){0.f, 0.f, 0.f, 0.f};

#pragma unroll
  for (int jt = 0; jt < 2; ++jt) {
    const int arow = (32 * w + 16 * jt + m) * 128 + q * 8;
    short8 ah[4], al[4];  // weight frags register-cached, reused over nt
#pragma unroll
    for (int kk = 0; kk < 4; ++kk) {
      ah[kk] = *(const short8*)(WkHi + arow + kk * 32);
      al[kk] = *(const short8*)(WkLo + arow + kk * 32);
    }
#pragma unroll
    for (int kk = 0; kk < 4; ++kk) {
      int co = (kk * 4 + q) * 8;
      short8 bh0 = *(const short8*)(xHi + rb[0] + (co ^ f8[0]));
      short8 bl0 = *(const short8*)(xLo + rb[0] + (co ^ f8[0]));
      short8 bh1 = *(const short8*)(xHi + rb[1] + (co ^ f8[1]));
      short8 bl1 = *(const short8*)(xLo + rb[1] + (co ^ f8[1]));
      acck[jt][0] = __builtin_amdgcn_mfma_f32_16x16x32_bf16(ah[kk], bh0, acck[jt][0], 0, 0, 0);
      acck[jt][1] = __builtin_amdgcn_mfma_f32_16x16x32_bf16(ah[kk], bh1, acck[jt][1], 0, 0, 0);
      acck[jt][0] = __builtin_amdgcn_mfma_f32_16x16x32_bf16(ah[kk], bl0, acck[jt][0], 0, 0, 0);
      acck[jt][1] = __builtin_amdgcn_mfma_f32_16x16x32_bf16(ah[kk], bl1, acck[jt][1], 0, 0, 0);
      acck[jt][0] = __builtin_amdgcn_mfma_f32_16x16x32_bf16(al[kk], bh0, acck[jt][0], 0, 0, 0);
      acck[jt][1] = __builtin_amdgcn_mfma_f32_16x16x32_bf16(al[kk], bh1, acck[jt][1], 0, 0, 0);
    }
  }

  // ---- ksum partial over this wave's 32 j ----
#pragma unroll
  for (int nt = 0; nt < 2; ++nt) {
    float s = 0.f;
#pragma unroll
    for (int jt = 0; jt < 2; ++jt)
      s += acck[jt][nt][0] + acck[jt][nt][1] + acck[jt][nt][2] + acck[jt][nt][3];
    s += __shfl_xor(s, 16, 64);
    s += __shfl_xor(s, 32, 64);
    if (q == 0) red1[w][nt * 16 + m] = s;
  }
  __syncthreads();  // B1: red1 ready; ALL pos LDS reads complete (buffer reusable)

  // ---- phase 3a: softmax-local (regs + red0/red1 only) ----
  float mw[2], sw[2];
#pragma unroll
  for (int nt = 0; nt < 2; ++nt) {
    int c = nt * 16 + m;
    float ss = red0[0][c] + red0[1][c] + red0[2][c] + red0[3][c];
    float ks = red1[0][c] + red1[1][c] + red1[2][c] + red1[3][c];
    float gl = (ss / (1e-9f + ss * ks)) * 1.44269504f;  // fold log2(e)
    float mx = gl * acck[0][nt][0];
#pragma unroll
    for (int jt = 0; jt < 2; ++jt)
#pragma unroll
      for (int r = 0; r < 4; ++r) {
        float e = gl * acck[jt][nt][r];
        acck[jt][nt][r] = e;  // log2-domain energy
        mx = fmaxf(mx, e);
      }
    mx = fmaxf(mx, __shfl_xor(mx, 16, 64));
    mx = fmaxf(mx, __shfl_xor(mx, 32, 64));
    float s = 0.f;
#pragma unroll
    for (int jt = 0; jt < 2; ++jt)
#pragma unroll
      for (int r = 0; r < 4; ++r) {
        float p = exp2f(acck[jt][nt][r] - mx);
        acck[jt][nt][r] = p;  // unnormalized attention
        s += p;
      }
    s += __shfl_xor(s, 16, 64);
    s += __shfl_xor(s, 32, 64);
    mw[nt] = mx;
    sw[nt] = s;
  }
  if (q == 0) {
#pragma unroll
    for (int nt = 0; nt < 2; ++nt) {
      red2[w][nt * 16 + m] = mw[nt];
      red3[w][nt * 16 + m] = sw[nt];
    }
  }

  // ---- phase 3b: re-stage FEAT tile (hi/lo) into the same LDS buffers ----
  {
#pragma unroll
    for (int it = 0; it < 2; ++it) {
      int i = 64 * it + 2 * g;
      float4 f0 = *(const float4*)(feat_g + (size_t)i * N_ + n4);
      float4 f1 = *(const float4*)(feat_g + (size_t)(i + 1) * N_ + n4);
      const float* F0 = (const float*)&f0;
      const float* F1 = (const float*)&f1;
      int c8 = (i >> 3) * 8;
      int ioff = i & 7;
#pragma unroll
      for (int d = 0; d < 4; ++d) {
        int n = n4 + d;
        int fn8 = ((n & 15) ^ ((n >> 2) & 7)) * 8;
        int hw = n * 128 + (c8 ^ fn8) + ioff;
        float y0 = F0[d], y1 = F1[d];
        unsigned fu = cvt_pk_bf16(y0, y1);
        *(unsigned*)(xHi + hw) = fu;
        float e0 = y0 - u16lo_f(fu);
        float e1 = y1 - u16hi_f(fu);
        *(unsigned*)(xLo + hw) = cvt_pk_bf16(e0, e1);
      }
    }
  }
  __syncthreads();  // B2: feat LDS + red2/red3 ready

  // ---- attscale combine ----
  float attscale[2];
#pragma unroll
  for (int nt = 0; nt < 2; ++nt) {
    int c = nt * 16 + m;
    float M = red2[0][c];
    M = fmaxf(M, red2[1][c]);
    M = fmaxf(M, red2[2][c]);
    M = fmaxf(M, red2[3][c]);
    float es = red3[0][c] * exp2f(red2[0][c] - M);
    es += red3[1][c] * exp2f(red2[1][c] - M);
    es += red3[2][c] * exp2f(red2[2][c] - M);
    es += red3[3][c] * exp2f(red2[3][c] - M);
    attscale[nt] = exp2f(mw[nt] - M) / es;  // es >= 1 (max-owning wave)
  }

  // ---- phase 4: v-GEMM (bf16, feat-hi from LDS) ----
  f32x4 accv[2][2];
#pragma unroll
  for (int jt = 0; jt < 2; ++jt)
#pragma unroll
    for (int nt = 0; nt < 2; ++nt) accv[jt][nt] = (f32x4){0.f, 0.f, 0.f, 0.f};

#pragma unroll
  for (int jt = 0; jt < 2; ++jt) {
    const int arow = (32 * w + 16 * jt + m) * 128 + q * 8;
    short8 ah[4];
#pragma unroll
    for (int kk = 0; kk < 4; ++kk) ah[kk] = *(const short8*)(WvHi + arow + kk * 32);
#pragma unroll
    for (int kk = 0; kk < 4; ++kk) {
      int co = (kk * 4 + q) * 8;
      short8 bh0 = *(const short8*)(xHi + rb[0] + (co ^ f8[0]));
      short8 bh1 = *(const short8*)(xHi + rb[1] + (co ^ f8[1]));
      accv[jt][0] = __builtin_amdgcn_mfma_f32_16x16x32_bf16(ah[kk], bh0, accv[jt][0], 0, 0, 0);
      accv[jt][1] = __builtin_amdgcn_mfma_f32_16x16x32_bf16(ah[kk], bh1, accv[jt][1], 0, 0, 0);
    }
  }

  // ---- epilogue: out = att*v + feature (fv = hi+lo LDS reconstruct, err ~2^-17) ----
  float* outp = out + (size_t)b * C_ * N_ + n0 + m;
#pragma unroll
  for (int jt = 0; jt < 2; ++jt) {
    const int jb = 32 * w + 16 * jt + 4 * q;
    const int cj = (jb >> 3) * 8;
    const int joff = jb & 7;  // 0 or 4: rows jb..jb+3 share one chunk
#pragma unroll
    for (int nt = 0; nt < 2; ++nt) {
      int hw = rb[nt] + (cj ^ f8[nt]) + joff;
      unsigned fh01 = *(const unsigned*)(xHi + hw);
      unsigned fl01 = *(const unsigned*)(xLo + hw);
      unsigned fh23 = *(const unsigned*)(xHi + hw + 2);
      unsigned fl23 = *(const unsigned*)(xLo + hw + 2);
      float fv0 = u16lo_f(fh01) + u16lo_f(fl01);
      float fv1 = u16hi_f(fh01) + u16hi_f(fl01);
      float fv2 = u16lo_f(fh23) + u16lo_f(fl23);
      float fv3 = u16hi_f(fh23) + u16hi_f(fl23);
      float as = attscale[nt];
      size_t base = (size_t)jb * N_ + nt * 16;
      outp[base] = fmaf(acck[jt][nt][0] * as, accv[jt][nt][0], fv0);
      outp[base + N_] = fmaf(acck[jt][nt][1] * as, accv[jt][nt][1], fv1);
      outp[base + (size_t)2 * N_] = fmaf(acck[jt][nt][2] * as, accv[jt][nt][2], fv2);
      outp[base + (size_t)3 * N_] = fmaf(acck[jt][nt][3] * as, accv[jt][nt][3], fv3);
    }
  }
}

extern "C" void kernel_launch(void* const* d_in, const int* in_sizes, int n_in,
                              void* d_out, int out_size, void* d_ws, size_t ws_size,
                              hipStream_t stream) {
  const float* feature = (const float*)d_in[0];
  const float* position = (const float*)d_in[1];
  const float* Wq = (const float*)d_in[2];
  const float* Wk = (const float*)d_in[3];
  const float* Wv = (const float*)d_in[4];
  float* out = (float*)d_out;

  char* ws = (char*)d_ws;
  float* wqsum = (float*)ws;                           // 512 B
  unsigned short* WkHi = (unsigned short*)(ws + 512);  // 32 KB each
  unsigned short* WkLo = (unsigned short*)(ws + 512 + 32768);
  unsigned short* WvHi = (unsigned short*)(ws + 512 + 65536);

  prep_kernel<<<64, 256, 0, stream>>>(Wq, Wk, Wv, wqsum, WkHi, WkLo, WvHi);
  csa_mfma_kernel<<<B_ * (N_ / TN), 256, 0, stream>>>(feature, position, wqsum,
                                                      WkHi, WkLo, WvHi, out);
}

// Round 6
// 420.821 us; speedup vs baseline: 1.2345x; 1.0364x over previous
//
#include <hip/hip_runtime.h>

#define B_ 16
#define C_ 128
#define N_ 16384
#define TN 32

typedef __attribute__((ext_vector_type(8))) short short8;
typedef __attribute__((ext_vector_type(4))) float f32x4;

__device__ inline unsigned short bf16_rn(float x) {
  unsigned u = __float_as_uint(x);
  unsigned r = u + 0x7FFFu + ((u >> 16) & 1u);
  return (unsigned short)(r >> 16);
}

// Packed f32x2 -> bf16x2 (RNE), 1 VALU inst. No builtin on gfx950 -> inline asm.
__device__ inline unsigned cvt_pk_bf16(float a, float b) {
  unsigned r;
  asm("v_cvt_pk_bf16_f32 %0, %1, %2" : "=v"(r) : "v"(a), "v"(b));
  return r;
}

__device__ inline float u16hi_f(unsigned u) { return __uint_as_float(u & 0xFFFF0000u); }
__device__ inline float u16lo_f(unsigned u) { return __uint_as_float(u << 16); }

// Merged prep: Wk -> bf16 hi/lo split (k-path keeps split precision),
// Wv -> bf16 hi only; block 0 computes wqsum[i] = sum_o Wq[o][i].
__global__ __launch_bounds__(256) void prep_kernel(
    const float* __restrict__ Wq, const float* __restrict__ Wk, const float* __restrict__ Wv,
    float* __restrict__ wqsum,
    unsigned short* __restrict__ WkHi, unsigned short* __restrict__ WkLo,
    unsigned short* __restrict__ WvHi) {
  int idx = blockIdx.x * 256 + threadIdx.x;  // 0..16383
  {
    float x = Wk[idx];
    unsigned short h = bf16_rn(x);
    WkHi[idx] = h;
    WkLo[idx] = bf16_rn(x - __uint_as_float(((unsigned)h) << 16));
  }
  WvHi[idx] = bf16_rn(Wv[idx]);
  if (blockIdx.x == 0 && threadIdx.x < C_) {
    int i = threadIdx.x;
    float s = 0.f;
#pragma unroll 8
    for (int o = 0; o < C_; ++o) s += Wq[o * C_ + i];
    wqsum[i] = s;
  }
}

// Main: one block per (batch, 32-col tile). 4 waves, j-split: wave w owns output
// channels [32w,32w+32) for all 32 cols. LDS time-multiplexed: xHi/xLo hold POS
// (hi/lo) for k-GEMM, then FEAT (hi/lo) for v-GEMM + residual. 18.4 KB LDS.
// __launch_bounds__(256,7): VGPR cap 73 > ~60 live set -> NO spill (R5 lesson:
// (256,8) cap 64 forced ~124MB spill traffic); 7 blocks/CU (28 waves, 87.5%).
// Weight frags loaded per-kk (8-reg live range; unrolled region lets the
// scheduler hoist within budget). Feat global loads issued BEFORE softmax so
// HBM latency overlaps it. Phases: stage pos(+sq->red0) | B0 | k-GEMM (split,
// 48 mfma) | ksum->red1 | B1 | feat loads + softmax-local(->red2/3) + feat
// convert->LDS | B2 | attscale + v-GEMM (bf16) + epilogue.
// LDS X layout: [n][i] bf16 rows of 128, 8-chunks XOR-swizzled f(n)=(n&15)^((n>>2)&7).
__global__ __launch_bounds__(256, 7) void csa_mfma_kernel(
    const float* __restrict__ feature, const float* __restrict__ position,
    const float* __restrict__ wqsum,
    const unsigned short* __restrict__ WkHi, const unsigned short* __restrict__ WkLo,
    const unsigned short* __restrict__ WvHi,
    float* __restrict__ out) {
  __shared__ unsigned short xHi[TN * 128];
  __shared__ unsigned short xLo[TN * 128];
  __shared__ float red0[4][TN];  // sq wave-partials (written during pos staging)
  __shared__ float red1[4][TN];  // ksum wave-partials
  __shared__ float red2[4][TN];  // per-wave local max (log2 domain)
  __shared__ float red3[4][TN];  // per-wave exp2-sum

  const int tid = threadIdx.x;
  const int lane = tid & 63;
  const int w = tid >> 6;   // wave: owns j in [32w, 32w+32)
  const int m = lane & 15;  // column-within-16 / A-row
  const int q = lane >> 4;  // quad
  const int b = blockIdx.x >> 9;
  const int n0 = (blockIdx.x & 511) * TN;

  const float* pos_g = position + (size_t)b * C_ * N_ + n0;
  const float* feat_g = feature + (size_t)b * C_ * N_ + n0;

  // staging thread mapping
  const int g = tid >> 3;        // 0..31 (wave w covers g in [8w,8w+8))
  const int n4 = (tid & 7) * 4;  // col group

  // per-column-tile LDS row bases for this lane (col n = nt*16 + m)
  int rb[2], f8[2];
#pragma unroll
  for (int nt = 0; nt < 2; ++nt) {
    int n = nt * 16 + m;
    rb[nt] = n * 128;
    f8[nt] = ((n & 15) ^ ((n >> 2) & 7)) * 8;
  }

  // ---- phase 1: stage POS tile (hi/lo) + sq partials on exact f32 ----
  {
    f32x4 sqa = (f32x4){0.f, 0.f, 0.f, 0.f};
#pragma unroll
    for (int it = 0; it < 2; ++it) {
      int i = 64 * it + 2 * g;  // even row; rows i, i+1
      float4 p0 = *(const float4*)(pos_g + (size_t)i * N_ + n4);
      float4 p1 = *(const float4*)(pos_g + (size_t)(i + 1) * N_ + n4);
      float2 wq2 = *(const float2*)(wqsum + i);
      const float* P0 = (const float*)&p0;
      const float* P1 = (const float*)&p1;
      int c8 = (i >> 3) * 8;
      int ioff = i & 7;  // even
#pragma unroll
      for (int d = 0; d < 4; ++d) {
        int n = n4 + d;
        int fn8 = ((n & 15) ^ ((n >> 2) & 7)) * 8;
        int hw = n * 128 + (c8 ^ fn8) + ioff;
        float x0 = P0[d], x1 = P1[d];
        unsigned hu = cvt_pk_bf16(x0, x1);
        *(unsigned*)(xHi + hw) = hu;
        float l0 = x0 - u16lo_f(hu);
        float l1 = x1 - u16hi_f(hu);
        *(unsigned*)(xLo + hw) = cvt_pk_bf16(l0, l1);
        sqa[d] = fmaf(wq2.x, x0, fmaf(wq2.y, x1, sqa[d]));
      }
    }
#pragma unroll
    for (int d = 0; d < 4; ++d) {
      float s = sqa[d];
      s += __shfl_xor(s, 8, 64);
      s += __shfl_xor(s, 16, 64);
      s += __shfl_xor(s, 32, 64);
      sqa[d] = s;
    }
    if (lane < 8) {
      *(float4*)&red0[w][lane * 4] = make_float4(sqa[0], sqa[1], sqa[2], sqa[3]);
    }
  }
  __syncthreads();  // B0: pos LDS + red0 ready

  // ---- phase 2: k-GEMM (split precision): k[j][n], j = 32w + 16jt + 4q + r ----
  f32x4 acck[2][2];
#pragma unroll
  for (int jt = 0; jt < 2; ++jt)
#pragma unroll
    for (int nt = 0; nt < 2; ++nt) acck[jt][nt] = (f32x4){0.f, 0.f, 0.f, 0.f};

#pragma unroll
  for (int jt = 0; jt < 2; ++jt) {
    const int arow = (32 * w + 16 * jt + m) * 128 + q * 8;
#pragma unroll
    for (int kk = 0; kk < 4; ++kk) {
      // per-kk weight loads: 8-VGPR live range (scheduler hoists within budget)
      short8 ah = *(const short8*)(WkHi + arow + kk * 32);
      short8 al = *(const short8*)(WkLo + arow + kk * 32);
      int co = (kk * 4 + q) * 8;
      short8 bh0 = *(const short8*)(xHi + rb[0] + (co ^ f8[0]));
      short8 bl0 = *(const short8*)(xLo + rb[0] + (co ^ f8[0]));
      short8 bh1 = *(const short8*)(xHi + rb[1] + (co ^ f8[1]));
      short8 bl1 = *(const short8*)(xLo + rb[1] + (co ^ f8[1]));
      acck[jt][0] = __builtin_amdgcn_mfma_f32_16x16x32_bf16(ah, bh0, acck[jt][0], 0, 0, 0);
      acck[jt][1] = __builtin_amdgcn_mfma_f32_16x16x32_bf16(ah, bh1, acck[jt][1], 0, 0, 0);
      acck[jt][0] = __builtin_amdgcn_mfma_f32_16x16x32_bf16(ah, bl0, acck[jt][0], 0, 0, 0);
      acck[jt][1] = __builtin_amdgcn_mfma_f32_16x16x32_bf16(ah, bl1, acck[jt][1], 0, 0, 0);
      acck[jt][0] = __builtin_amdgcn_mfma_f32_16x16x32_bf16(al, bh0, acck[jt][0], 0, 0, 0);
      acck[jt][1] = __builtin_amdgcn_mfma_f32_16x16x32_bf16(al, bh1, acck[jt][1], 0, 0, 0);
    }
  }

  // ---- ksum partial over this wave's 32 j ----
#pragma unroll
  for (int nt = 0; nt < 2; ++nt) {
    float s = 0.f;
#pragma unroll
    for (int jt = 0; jt < 2; ++jt)
      s += acck[jt][nt][0] + acck[jt][nt][1] + acck[jt][nt][2] + acck[jt][nt][3];
    s += __shfl_xor(s, 16, 64);
    s += __shfl_xor(s, 32, 64);
    if (q == 0) red1[w][nt * 16 + m] = s;
  }
  __syncthreads();  // B1: red1 ready; ALL pos LDS reads complete (buffer reusable)

  // ---- phase 3: issue feat loads FIRST (latency overlaps softmax below) ----
  float4 F0[2], F1[2];
#pragma unroll
  for (int it = 0; it < 2; ++it) {
    int i = 64 * it + 2 * g;
    F0[it] = *(const float4*)(feat_g + (size_t)i * N_ + n4);
    F1[it] = *(const float4*)(feat_g + (size_t)(i + 1) * N_ + n4);
  }

  // ---- softmax-local (regs + red0/red1 only) ----
  float mw[2], sw[2];
#pragma unroll
  for (int nt = 0; nt < 2; ++nt) {
    int c = nt * 16 + m;
    float ss = red0[0][c] + red0[1][c] + red0[2][c] + red0[3][c];
    float ks = red1[0][c] + red1[1][c] + red1[2][c] + red1[3][c];
    float gl = (ss / (1e-9f + ss * ks)) * 1.44269504f;  // fold log2(e)
    float mx = gl * acck[0][nt][0];
#pragma unroll
    for (int jt = 0; jt < 2; ++jt)
#pragma unroll
      for (int r = 0; r < 4; ++r) {
        float e = gl * acck[jt][nt][r];
        acck[jt][nt][r] = e;  // log2-domain energy
        mx = fmaxf(mx, e);
      }
    mx = fmaxf(mx, __shfl_xor(mx, 16, 64));
    mx = fmaxf(mx, __shfl_xor(mx, 32, 64));
    float s = 0.f;
#pragma unroll
    for (int jt = 0; jt < 2; ++jt)
#pragma unroll
      for (int r = 0; r < 4; ++r) {
        float p = exp2f(acck[jt][nt][r] - mx);
        acck[jt][nt][r] = p;  // unnormalized attention
        s += p;
      }
    s += __shfl_xor(s, 16, 64);
    s += __shfl_xor(s, 32, 64);
    mw[nt] = mx;
    sw[nt] = s;
  }
  if (q == 0) {
#pragma unroll
    for (int nt = 0; nt < 2; ++nt) {
      red2[w][nt * 16 + m] = mw[nt];
      red3[w][nt * 16 + m] = sw[nt];
    }
  }

  // ---- convert + write FEAT tile (hi/lo) into the same LDS buffers ----
#pragma unroll
  for (int it = 0; it < 2; ++it) {
    int i = 64 * it + 2 * g;
    const float* F0p = (const float*)&F0[it];
    const float* F1p = (const float*)&F1[it];
    int c8 = (i >> 3) * 8;
    int ioff = i & 7;
#pragma unroll
    for (int d = 0; d < 4; ++d) {
      int n = n4 + d;
      int fn8 = ((n & 15) ^ ((n >> 2) & 7)) * 8;
      int hw = n * 128 + (c8 ^ fn8) + ioff;
      float y0 = F0p[d], y1 = F1p[d];
      unsigned fu = cvt_pk_bf16(y0, y1);
      *(unsigned*)(xHi + hw) = fu;
      float e0 = y0 - u16lo_f(fu);
      float e1 = y1 - u16hi_f(fu);
      *(unsigned*)(xLo + hw) = cvt_pk_bf16(e0, e1);
    }
  }
  __syncthreads();  // B2: feat LDS + red2/red3 ready

  // ---- attscale combine ----
  float attscale[2];
#pragma unroll
  for (int nt = 0; nt < 2; ++nt) {
    int c = nt * 16 + m;
    float M = red2[0][c];
    M = fmaxf(M, red2[1][c]);
    M = fmaxf(M, red2[2][c]);
    M = fmaxf(M, red2[3][c]);
    float es = red3[0][c] * exp2f(red2[0][c] - M);
    es += red3[1][c] * exp2f(red2[1][c] - M);
    es += red3[2][c] * exp2f(red2[2][c] - M);
    es += red3[3][c] * exp2f(red2[3][c] - M);
    attscale[nt] = exp2f(mw[nt] - M) / es;  // es >= 1 (max-owning wave)
  }

  // ---- phase 4: v-GEMM (bf16, feat-hi from LDS) ----
  f32x4 accv[2][2];
#pragma unroll
  for (int jt = 0; jt < 2; ++jt)
#pragma unroll
    for (int nt = 0; nt < 2; ++nt) accv[jt][nt] = (f32x4){0.f, 0.f, 0.f, 0.f};

#pragma unroll
  for (int jt = 0; jt < 2; ++jt) {
    const int arow = (32 * w + 16 * jt + m) * 128 + q * 8;
#pragma unroll
    for (int kk = 0; kk < 4; ++kk) {
      short8 vh = *(const short8*)(WvHi + arow + kk * 32);
      int co = (kk * 4 + q) * 8;
      short8 bh0 = *(const short8*)(xHi + rb[0] + (co ^ f8[0]));
      short8 bh1 = *(const short8*)(xHi + rb[1] + (co ^ f8[1]));
      accv[jt][0] = __builtin_amdgcn_mfma_f32_16x16x32_bf16(vh, bh0, accv[jt][0], 0, 0, 0);
      accv[jt][1] = __builtin_amdgcn_mfma_f32_16x16x32_bf16(vh, bh1, accv[jt][1], 0, 0, 0);
    }
  }

  // ---- epilogue: out = att*v + feature (fv = hi+lo LDS reconstruct, err ~2^-17) ----
  float* outp = out + (size_t)b * C_ * N_ + n0 + m;
#pragma unroll
  for (int jt = 0; jt < 2; ++jt) {
    const int jb = 32 * w + 16 * jt + 4 * q;
    const int cj = (jb >> 3) * 8;
    const int joff = jb & 7;  // 0 or 4: rows jb..jb+3 share one chunk
#pragma unroll
    for (int nt = 0; nt < 2; ++nt) {
      int hw = rb[nt] + (cj ^ f8[nt]) + joff;
      unsigned fh01 = *(const unsigned*)(xHi + hw);
      unsigned fl01 = *(const unsigned*)(xLo + hw);
      unsigned fh23 = *(const unsigned*)(xHi + hw + 2);
      unsigned fl23 = *(const unsigned*)(xLo + hw + 2);
      float fv0 = u16lo_f(fh01) + u16lo_f(fl01);
      float fv1 = u16hi_f(fh01) + u16hi_f(fl01);
      float fv2 = u16lo_f(fh23) + u16lo_f(fl23);
      float fv3 = u16hi_f(fh23) + u16hi_f(fl23);
      float as = attscale[nt];
      size_t base = (size_t)jb * N_ + nt * 16;
      outp[base] = fmaf(acck[jt][nt][0] * as, accv[jt][nt][0], fv0);
      outp[base + N_] = fmaf(acck[jt][nt][1] * as, accv[jt][nt][1], fv1);
      outp[base + (size_t)2 * N_] = fmaf(acck[jt][nt][2] * as, accv[jt][nt][2], fv2);
      outp[base + (size_t)3 * N_] = fmaf(acck[jt][nt][3] * as, accv[jt][nt][3], fv3);
    }
  }
}

extern "C" void kernel_launch(void* const* d_in, const int* in_sizes, int n_in,
                              void* d_out, int out_size, void* d_ws, size_t ws_size,
                              hipStream_t stream) {
  const float* feature = (const float*)d_in[0];
  const float* position = (const float*)d_in[1];
  const float* Wq = (const float*)d_in[2];
  const float* Wk = (const float*)d_in[3];
  const float* Wv = (const float*)d_in[4];
  float* out = (float*)d_out;

  char* ws = (char*)d_ws;
  float* wqsum = (float*)ws;                           // 512 B
  unsigned short* WkHi = (unsigned short*)(ws + 512);  // 32 KB each
  unsigned short* WkLo = (unsigned short*)(ws + 512 + 32768);
  unsigned short* WvHi = (unsigned short*)(ws + 512 + 65536);

  prep_kernel<<<64, 256, 0, stream>>>(Wq, Wk, Wv, wqsum, WkHi, WkLo, WvHi);
  csa_mfma_kernel<<<B_ * (N_ / TN), 256, 0, stream>>>(feature, position, wqsum,
                                                      WkHi, WkLo, WvHi, out);
}